// Round 6
// baseline (330.092 us; speedup 1.0000x reference)
//
#include <hip/hip_runtime.h>
#include <cstdint>

#define NN 100000
#define CH 128
#define NT_BLK 32
#define SCAN_B 256

typedef __bf16 bf16x8 __attribute__((ext_vector_type(8)));
typedef __bf16 bf16x4 __attribute__((ext_vector_type(4)));
typedef float  f32x4  __attribute__((ext_vector_type(4)));

__device__ __forceinline__ float b2f(unsigned short u) {
    union { unsigned int i; float f; } v; v.i = ((unsigned int)u) << 16; return v.f;
}

// ================= CSR build =================

__global__ void k_count(const int* __restrict__ dst, int* __restrict__ cnt, int E) {
    int e = blockIdx.x * blockDim.x + threadIdx.x;
    if (e < E) atomicAdd(&cnt[dst[e]], 1);
}

// Fused scan + weight-convert, split by block range (see R5 notes):
// blocks [0,nb): per-block redundant prefix (grid-stride reduce over cnt, L2-hot)
// + Hillis-Steele scan of own 256 -> rowptr, cursor. blocks [nb,nb+32): wconv.
__global__ void k_scan_wconv(const int* __restrict__ cnt, int* __restrict__ rowptr,
                             int* __restrict__ cursor, int n, int E, int nb,
                             const float* __restrict__ W1l, const float* __restrict__ W1r,
                             const float* __restrict__ W2l, const float* __restrict__ W2r,
                             __bf16* __restrict__ wB) {
    const int t = threadIdx.x;
    if ((int)blockIdx.x >= nb) {
        int tid = ((int)blockIdx.x - nb) * SCAN_B + t;   // 0..8191
        int l    = tid >> 12;
        int rem  = tid & 4095;
        int kt   = rem >> 9;
        int nt   = (rem >> 6) & 7;
        int lane = rem & 63;
        const float* Wl = l ? W2l : W1l;
        const float* Wr = l ? W2r : W1r;
        int nn = nt * 16 + (lane & 15);
        int k0 = kt * 32 + (lane >> 4) * 8;
        bf16x8 v;
#pragma unroll
        for (int i = 0; i < 8; ++i) {
            int k = k0 + i;
            float f = (k < CH) ? Wl[k * CH + nn] : Wr[(k - CH) * CH + nn];
            v[i] = (__bf16)f;
        }
        *reinterpret_cast<bf16x8*>(wB + (size_t)tid * 8) = v;
        return;
    }
    __shared__ int sd[SCAN_B];
    const int lim = (int)blockIdx.x * SCAN_B;
    int s = 0;
    for (int j = t; j < lim; j += SCAN_B) s += cnt[j];
    sd[t] = s;
    __syncthreads();
    for (int off = SCAN_B / 2; off > 0; off >>= 1) {
        if (t < off) sd[t] += sd[t + off];
        __syncthreads();
    }
    const int base = sd[0];
    __syncthreads();
    const int i = lim + t;
    const int v = (i < n) ? cnt[i] : 0;
    sd[t] = v;
    __syncthreads();
    for (int off = 1; off < SCAN_B; off <<= 1) {
        int tv = (t >= off) ? sd[t - off] : 0;
        __syncthreads();
        sd[t] += tv;
        __syncthreads();
    }
    if (i < n) {
        const int excl = sd[t] - v + base;
        rowptr[i] = excl;
        cursor[i] = excl;
    }
    if (i == 0) rowptr[n] = E;
}

__global__ void k_fill(const int* __restrict__ src, const int* __restrict__ dst,
                       int* __restrict__ cursor, int* __restrict__ csr, int E) {
    int e = blockIdx.x * blockDim.x + threadIdx.x;
    if (e >= E) return;
    int slot = atomicAdd(&cursor[dst[e]], 1);
    csr[slot] = src[e];
}

// ================= fused SAGE layer (MFMA) =================
// (structure per R4; Phase 1 now uses MASKED unroll-4 batches: indices clamped
// to the last valid slot, validity folded into the FMA -> all 4 loads of every
// batch issue concurrently, no serial remainder chain.)
template<bool FC, typename FT>
__global__ __launch_bounds__(256) void k_layer(
    const FT* __restrict__ feat,
    const int* __restrict__ rowptr, const int* __restrict__ csr,
    const bf16x8* __restrict__ wfrag,
    const float* __restrict__ bias,
    const float* __restrict__ Wfc, const float* __restrict__ bfc,
    void* __restrict__ outv)
{
    __shared__ unsigned short a_lds[NT_BLK * 256];   // 16 KB
    __shared__ float red[4][16];
    char* lb = (char*)a_lds;
    const int tid = threadIdx.x;
    const int node0 = blockIdx.x * NT_BLK;

    const int g = tid >> 5;
    const int q = tid & 31;

    auto loadrow = [&](int idx) -> float4 {
        if constexpr (sizeof(FT) == 2) {
            const ushort4 u = *reinterpret_cast<const ushort4*>(
                (const unsigned short*)feat + (size_t)idx * CH + q * 4);
            return make_float4(b2f(u.x), b2f(u.y), b2f(u.z), b2f(u.w));
        } else {
            return *reinterpret_cast<const float4*>((const float*)feat + (size_t)idx * CH + q * 4);
        }
    };

#pragma unroll
    for (int it = 0; it < NT_BLK / 8; ++it) {
        const int r = it * 8 + g;
        const int node = node0 + r;
        const int swz = (r & 7) << 4;
        float4 s = make_float4(0.f, 0.f, 0.f, 0.f);
        bf16x4 k2 = {(__bf16)0.f, (__bf16)0.f, (__bf16)0.f, (__bf16)0.f};
        if (node < NN) {
            const int r0 = rowptr[node], r1 = rowptr[node + 1];
            const int last = r1 - 1;
            for (int rr = r0; rr < r1; rr += 4) {
                const int i0 = csr[rr];
                const int i1 = csr[min(rr + 1, last)];
                const int i2 = csr[min(rr + 2, last)];
                const int i3 = csr[min(rr + 3, last)];
                const float m1 = (rr + 1 < r1) ? 1.f : 0.f;
                const float m2 = (rr + 2 < r1) ? 1.f : 0.f;
                const float m3 = (rr + 3 < r1) ? 1.f : 0.f;
                const float4 v0 = loadrow(i0), v1 = loadrow(i1), v2 = loadrow(i2), v3 = loadrow(i3);
                s.x += v0.x + m1 * v1.x + m2 * v2.x + m3 * v3.x;
                s.y += v0.y + m1 * v1.y + m2 * v2.y + m3 * v3.y;
                s.z += v0.z + m1 * v1.z + m2 * v2.z + m3 * v3.z;
                s.w += v0.w + m1 * v1.w + m2 * v2.w + m3 * v3.w;
            }
            const float invd = 1.0f / fmaxf((float)(r1 - r0), 1.0f);
            s.x *= invd; s.y *= invd; s.z *= invd; s.w *= invd;
            if constexpr (sizeof(FT) == 2) {
                const ushort4 u = *reinterpret_cast<const ushort4*>(
                    (const unsigned short*)feat + (size_t)node * CH + q * 4);
                k2 = *reinterpret_cast<const bf16x4*>(&u);
            } else {
                const float4 sv = *reinterpret_cast<const float4*>((const float*)feat + (size_t)node * CH + q * 4);
                k2[0] = (__bf16)sv.x; k2[1] = (__bf16)sv.y; k2[2] = (__bf16)sv.z; k2[3] = (__bf16)sv.w;
            }
        }
        bf16x4 a;
        a[0] = (__bf16)s.x; a[1] = (__bf16)s.y; a[2] = (__bf16)s.z; a[3] = (__bf16)s.w;
        *reinterpret_cast<bf16x4*>(lb + r * 512 + ((q * 8) ^ swz)) = a;
        *reinterpret_cast<bf16x4*>(lb + r * 512 + ((256 + q * 8) ^ swz)) = k2;
    }
    __syncthreads();

    const int lane = tid & 63;
    const int w = tid >> 6;
    const int rows16 = (w >> 1) * 16;
    const int ntbase = (w & 1) * 4;
    const int row = rows16 + (lane & 15);
    const int rswz = (row & 7) << 4;
    const int abase = row * 512;
    const int asub = (lane >> 4) * 16;

    f32x4 acc[4];
#pragma unroll
    for (int nt = 0; nt < 4; ++nt) { acc[nt][0] = 0.f; acc[nt][1] = 0.f; acc[nt][2] = 0.f; acc[nt][3] = 0.f; }

#pragma unroll
    for (int kt = 0; kt < 8; ++kt) {
        const bf16x8 a = *reinterpret_cast<const bf16x8*>(lb + abase + ((kt * 64 + asub) ^ rswz));
        const bf16x8* bp = wfrag + kt * 512 + ntbase * 64 + lane;
#pragma unroll
        for (int nt = 0; nt < 4; ++nt) {
            const bf16x8 b = bp[nt * 64];
            acc[nt] = __builtin_amdgcn_mfma_f32_16x16x32_bf16(a, b, acc[nt], 0, 0, 0);
        }
    }

    const int nbase = lane & 15;
    if (!FC) {
        __bf16* out = (__bf16*)outv;
#pragma unroll
        for (int nt = 0; nt < 4; ++nt) {
            const int ch = (ntbase + nt) * 16 + nbase;
            const float bv = bias[ch];
#pragma unroll
            for (int rr = 0; rr < 4; ++rr) {
                const int node = node0 + rows16 + (lane >> 4) * 4 + rr;
                if (node < NN)
                    out[(size_t)node * CH + ch] = (__bf16)fmaxf(acc[nt][rr] + bv, 0.0f);
            }
        }
    } else {
        float* out = (float*)outv;
        float p[4] = {0.f, 0.f, 0.f, 0.f};
#pragma unroll
        for (int nt = 0; nt < 4; ++nt) {
            const int ch = (ntbase + nt) * 16 + nbase;
            const float bv = bias[ch];
            const float wf = Wfc[ch];
#pragma unroll
            for (int rr = 0; rr < 4; ++rr)
                p[rr] += fmaxf(acc[nt][rr] + bv, 0.0f) * wf;
        }
#pragma unroll
        for (int m = 1; m < 16; m <<= 1) {
#pragma unroll
            for (int rr = 0; rr < 4; ++rr) p[rr] += __shfl_xor(p[rr], m);
        }
        if (nbase == 0) {
#pragma unroll
            for (int rr = 0; rr < 4; ++rr)
                red[w][(lane >> 4) * 4 + rr] = p[rr];
        }
        __syncthreads();
        if (tid < NT_BLK) {
            const int rloc = tid;
            const float z = (rloc < 16 ? red[0][rloc] + red[1][rloc]
                                       : red[2][rloc - 16] + red[3][rloc - 16]) + bfc[0];
            const int node = node0 + rloc;
            if (node < NN) out[node] = 1.0f / (1.0f + expf(-z));
        }
    }
}

// ================= launch =================

extern "C" void kernel_launch(void* const* d_in, const int* in_sizes, int n_in,
                              void* d_out, int out_size, void* d_ws, size_t ws_size,
                              hipStream_t stream) {
    const float* x   = (const float*)d_in[0];
    const int*   ei  = (const int*)d_in[1];
    const float* W1l = (const float*)d_in[2];
    const float* W1r = (const float*)d_in[3];
    const float* b1  = (const float*)d_in[4];
    const float* W2l = (const float*)d_in[5];
    const float* W2r = (const float*)d_in[6];
    const float* b2  = (const float*)d_in[7];
    const float* Wfc = (const float*)d_in[8];
    const float* bfc = (const float*)d_in[9];

    const int E = in_sizes[1] / 2;
    const int* src = ei;
    const int* dst = ei + E;

    // ws: h1 [NN*CH bf16] | wB [65536 bf16] | cnt [NN] | cur [NN] | rowptr [NN+1] | csr [E]
    unsigned short* h1 = (unsigned short*)d_ws;
    __bf16* wB     = (__bf16*)(h1 + (size_t)NN * CH);
    int*    cnt    = (int*)(wB + 65536);
    int*    cur    = cnt + NN;
    int*    rowptr = cur + NN;
    int*    csr    = rowptr + NN + 1;

    const int nb = (NN + SCAN_B - 1) / SCAN_B;   // 391

    hipMemsetAsync(cnt, 0, (size_t)NN * sizeof(int), stream);
    k_count<<<(E + 255) / 256, 256, 0, stream>>>(dst, cnt, E);
    k_scan_wconv<<<nb + 32, SCAN_B, 0, stream>>>(cnt, rowptr, cur, NN, E, nb,
                                                 W1l, W1r, W2l, W2r, wB);
    k_fill<<<(E + 255) / 256, 256, 0, stream>>>(src, dst, cur, csr, E);

    const int blocks = (NN + NT_BLK - 1) / NT_BLK;   // 3125
    k_layer<false, float><<<blocks, 256, 0, stream>>>(
        x, rowptr, csr, (const bf16x8*)wB, b1, Wfc, bfc, h1);
    k_layer<true, unsigned short><<<blocks, 256, 0, stream>>>(
        h1, rowptr, csr, (const bf16x8*)(wB + 32768), b2, Wfc, bfc, d_out);
}

// Round 7
// 263.653 us; speedup vs baseline: 1.2520x; 1.2520x over previous
//
#include <hip/hip_runtime.h>
#include <cstdint>

#define NN 100000
#define CH 128
#define NT_BLK 32
#define SCAN_B 256

typedef __bf16 bf16x8 __attribute__((ext_vector_type(8)));
typedef __bf16 bf16x4 __attribute__((ext_vector_type(4)));
typedef float  f32x4  __attribute__((ext_vector_type(4)));

__device__ __forceinline__ float b2f(unsigned short u) {
    union { unsigned int i; float f; } v; v.i = ((unsigned int)u) << 16; return v.f;
}

// ================= fused: edge-count + x->bf16 convert =================
__global__ void k_count_xconv(const int* __restrict__ dst, int* __restrict__ cnt, int E,
                              const float* __restrict__ x, unsigned short* __restrict__ xb,
                              int cb) {
    const int b = blockIdx.x;
    if (b < cb) {
        int e = b * 256 + threadIdx.x;
        if (e < E) atomicAdd(&cnt[dst[e]], 1);
        return;
    }
    const size_t base = ((size_t)(b - cb) * 256 + threadIdx.x) * 8;
    if (base < (size_t)NN * CH) {
        const float4 a = *reinterpret_cast<const float4*>(x + base);
        const float4 c = *reinterpret_cast<const float4*>(x + base + 4);
        bf16x8 o;
        o[0] = (__bf16)a.x; o[1] = (__bf16)a.y; o[2] = (__bf16)a.z; o[3] = (__bf16)a.w;
        o[4] = (__bf16)c.x; o[5] = (__bf16)c.y; o[6] = (__bf16)c.z; o[7] = (__bf16)c.w;
        *reinterpret_cast<bf16x8*>(xb + base) = o;
    }
}

// ================= fused: per-block scan + weight convert =================
// blocks [0,nb): block-local exclusive scan of cnt -> rowptr, totals -> bsum.
// blocks [nb,nb+32): [Wl;Wr] (256x128, both layers) -> bf16 MFMA fragments
//   [layer][kt:8][nt:8][lane:64][8]: elem i = B[kt*32+(lane>>4)*8+i][nt*16+(lane&15)]
__global__ void k_scan_wb(const int* __restrict__ cnt, int* __restrict__ rowptr,
                          int* __restrict__ bsum, int n, int nb,
                          const float* __restrict__ W1l, const float* __restrict__ W1r,
                          const float* __restrict__ W2l, const float* __restrict__ W2r,
                          __bf16* __restrict__ wB) {
    const int t = threadIdx.x;
    if ((int)blockIdx.x >= nb) {
        int tid = ((int)blockIdx.x - nb) * SCAN_B + t;   // 0..8191
        int l    = tid >> 12;
        int rem  = tid & 4095;
        int kt   = rem >> 9;
        int nt   = (rem >> 6) & 7;
        int lane = rem & 63;
        const float* Wl = l ? W2l : W1l;
        const float* Wr = l ? W2r : W1r;
        int nn = nt * 16 + (lane & 15);
        int k0 = kt * 32 + (lane >> 4) * 8;
        bf16x8 v;
#pragma unroll
        for (int i = 0; i < 8; ++i) {
            int k = k0 + i;
            float f = (k < CH) ? Wl[k * CH + nn] : Wr[(k - CH) * CH + nn];
            v[i] = (__bf16)f;
        }
        *reinterpret_cast<bf16x8*>(wB + (size_t)tid * 8) = v;
        return;
    }
    __shared__ int tmp[SCAN_B];
    int i = blockIdx.x * SCAN_B + t;
    int v = (i < n) ? cnt[i] : 0;
    tmp[t] = v;
    __syncthreads();
    for (int off = 1; off < SCAN_B; off <<= 1) {
        int tv = (t >= off) ? tmp[t - off] : 0;
        __syncthreads();
        tmp[t] += tv;
        __syncthreads();
    }
    if (i < n) rowptr[i] = tmp[t] - v;
    if (t == SCAN_B - 1) bsum[blockIdx.x] = tmp[SCAN_B - 1];
}

// add prefix of block totals (<=391 entries: <=2 loads/thread), init fill cursor
__global__ void k_scan_add(int* __restrict__ rowptr, const int* __restrict__ bsum,
                           int* __restrict__ cursor, int n, int E) {
    __shared__ int sd[SCAN_B];
    const int t = threadIdx.x;
    int s = 0;
    for (int j = t; j < (int)blockIdx.x; j += SCAN_B) s += bsum[j];
    sd[t] = s;
    __syncthreads();
    for (int off = SCAN_B / 2; off > 0; off >>= 1) {
        if (t < off) sd[t] += sd[t + off];
        __syncthreads();
    }
    const int base = sd[0];
    int i = blockIdx.x * SCAN_B + t;
    if (i < n) {
        int v = rowptr[i] + base;
        rowptr[i] = v;
        cursor[i] = v;
    }
    if (i == 0) rowptr[n] = E;
}

__global__ void k_fill(const int* __restrict__ src, const int* __restrict__ dst,
                       int* __restrict__ cursor, int* __restrict__ csr, int E) {
    int e = blockIdx.x * blockDim.x + threadIdx.x;
    if (e >= E) return;
    int slot = atomicAdd(&cursor[dst[e]], 1);
    csr[slot] = src[e];
}

// ================= fused SAGE layer (MFMA) =================
// Phase 1: bf16 gather-mean, MASKED unroll-8 (8 ushort4 loads in flight/lane).
// Phase 2: per R5. FC=true: fused [128->1] head + sigmoid.
template<bool FC>
__global__ __launch_bounds__(256) void k_layer(
    const unsigned short* __restrict__ feat,
    const int* __restrict__ rowptr, const int* __restrict__ csr,
    const bf16x8* __restrict__ wfrag,
    const float* __restrict__ bias,
    const float* __restrict__ Wfc, const float* __restrict__ bfc,
    void* __restrict__ outv)
{
    __shared__ unsigned short a_lds[NT_BLK * 256];   // 16 KB
    __shared__ float red[4][16];
    char* lb = (char*)a_lds;
    const int tid = threadIdx.x;
    const int node0 = blockIdx.x * NT_BLK;

    const int g = tid >> 5;
    const int q = tid & 31;

#pragma unroll
    for (int it = 0; it < NT_BLK / 8; ++it) {
        const int r = it * 8 + g;
        const int node = node0 + r;
        const int swz = (r & 7) << 4;
        float4 s = make_float4(0.f, 0.f, 0.f, 0.f);
        bf16x4 k2 = {(__bf16)0.f, (__bf16)0.f, (__bf16)0.f, (__bf16)0.f};
        if (node < NN) {
            const int r0 = rowptr[node], r1 = rowptr[node + 1];
            const int last = r1 - 1;
            for (int rr = r0; rr < r1; rr += 8) {
                ushort4 uv[8];
                float mk[8];
#pragma unroll
                for (int u = 0; u < 8; ++u) {
                    const int p = rr + u;
                    const int idx = csr[p <= last ? p : last];
                    uv[u] = *reinterpret_cast<const ushort4*>(feat + (size_t)idx * CH + q * 4);
                    mk[u] = (p < r1) ? 1.f : 0.f;
                }
#pragma unroll
                for (int u = 0; u < 8; ++u) {
                    s.x += mk[u] * b2f(uv[u].x);
                    s.y += mk[u] * b2f(uv[u].y);
                    s.z += mk[u] * b2f(uv[u].z);
                    s.w += mk[u] * b2f(uv[u].w);
                }
            }
            const float invd = 1.0f / fmaxf((float)(r1 - r0), 1.0f);
            s.x *= invd; s.y *= invd; s.z *= invd; s.w *= invd;
            const ushort4 u = *reinterpret_cast<const ushort4*>(feat + (size_t)node * CH + q * 4);
            k2 = *reinterpret_cast<const bf16x4*>(&u);   // exact bit copy
        }
        bf16x4 a;
        a[0] = (__bf16)s.x; a[1] = (__bf16)s.y; a[2] = (__bf16)s.z; a[3] = (__bf16)s.w;
        *reinterpret_cast<bf16x4*>(lb + r * 512 + ((q * 8) ^ swz)) = a;
        *reinterpret_cast<bf16x4*>(lb + r * 512 + ((256 + q * 8) ^ swz)) = k2;
    }
    __syncthreads();

    const int lane = tid & 63;
    const int w = tid >> 6;
    const int rows16 = (w >> 1) * 16;
    const int ntbase = (w & 1) * 4;
    const int row = rows16 + (lane & 15);
    const int rswz = (row & 7) << 4;
    const int abase = row * 512;
    const int asub = (lane >> 4) * 16;

    f32x4 acc[4];
#pragma unroll
    for (int nt = 0; nt < 4; ++nt) { acc[nt][0] = 0.f; acc[nt][1] = 0.f; acc[nt][2] = 0.f; acc[nt][3] = 0.f; }

#pragma unroll
    for (int kt = 0; kt < 8; ++kt) {
        const bf16x8 a = *reinterpret_cast<const bf16x8*>(lb + abase + ((kt * 64 + asub) ^ rswz));
        const bf16x8* bp = wfrag + kt * 512 + ntbase * 64 + lane;
#pragma unroll
        for (int nt = 0; nt < 4; ++nt) {
            const bf16x8 b = bp[nt * 64];
            acc[nt] = __builtin_amdgcn_mfma_f32_16x16x32_bf16(a, b, acc[nt], 0, 0, 0);
        }
    }

    const int nbase = lane & 15;
    if (!FC) {
        __bf16* out = (__bf16*)outv;
#pragma unroll
        for (int nt = 0; nt < 4; ++nt) {
            const int ch = (ntbase + nt) * 16 + nbase;
            const float bv = bias[ch];
#pragma unroll
            for (int rr = 0; rr < 4; ++rr) {
                const int node = node0 + rows16 + (lane >> 4) * 4 + rr;
                if (node < NN)
                    out[(size_t)node * CH + ch] = (__bf16)fmaxf(acc[nt][rr] + bv, 0.0f);
            }
        }
    } else {
        float* out = (float*)outv;
        float p[4] = {0.f, 0.f, 0.f, 0.f};
#pragma unroll
        for (int nt = 0; nt < 4; ++nt) {
            const int ch = (ntbase + nt) * 16 + nbase;
            const float bv = bias[ch];
            const float wf = Wfc[ch];
#pragma unroll
            for (int rr = 0; rr < 4; ++rr)
                p[rr] += fmaxf(acc[nt][rr] + bv, 0.0f) * wf;
        }
#pragma unroll
        for (int m = 1; m < 16; m <<= 1) {
#pragma unroll
            for (int rr = 0; rr < 4; ++rr) p[rr] += __shfl_xor(p[rr], m);
        }
        if (nbase == 0) {
#pragma unroll
            for (int rr = 0; rr < 4; ++rr)
                red[w][(lane >> 4) * 4 + rr] = p[rr];
        }
        __syncthreads();
        if (tid < NT_BLK) {
            const int rloc = tid;
            const float z = (rloc < 16 ? red[0][rloc] + red[1][rloc]
                                       : red[2][rloc - 16] + red[3][rloc - 16]) + bfc[0];
            const int node = node0 + rloc;
            if (node < NN) out[node] = 1.0f / (1.0f + expf(-z));
        }
    }
}

// ================= launch =================

extern "C" void kernel_launch(void* const* d_in, const int* in_sizes, int n_in,
                              void* d_out, int out_size, void* d_ws, size_t ws_size,
                              hipStream_t stream) {
    const float* x   = (const float*)d_in[0];
    const int*   ei  = (const int*)d_in[1];
    const float* W1l = (const float*)d_in[2];
    const float* W1r = (const float*)d_in[3];
    const float* b1  = (const float*)d_in[4];
    const float* W2l = (const float*)d_in[5];
    const float* W2r = (const float*)d_in[6];
    const float* b2  = (const float*)d_in[7];
    const float* Wfc = (const float*)d_in[8];
    const float* bfc = (const float*)d_in[9];

    const int E = in_sizes[1] / 2;
    const int* src = ei;
    const int* dst = ei + E;

    // ws: h1 [NN*CH bf16] | xb [NN*CH bf16] | wB [65536 bf16] | cnt | cur | rowptr | bsum | csr
    unsigned short* h1 = (unsigned short*)d_ws;
    unsigned short* xb = h1 + (size_t)NN * CH;
    __bf16* wB     = (__bf16*)(xb + (size_t)NN * CH);
    int*    cnt    = (int*)(wB + 65536);
    int*    cur    = cnt + NN;
    int*    rowptr = cur + NN;
    int*    bsum   = rowptr + NN + 1;
    int*    csr    = bsum + 512;

    const int nb = (NN + SCAN_B - 1) / SCAN_B;      // 391
    const int cb = (E + 255) / 256;                 // 2500
    const int xcb = (NN * CH) / 2048;               // 6250

    hipMemsetAsync(cnt, 0, (size_t)NN * sizeof(int), stream);
    k_count_xconv<<<cb + xcb, 256, 0, stream>>>(dst, cnt, E, x, xb, cb);
    k_scan_wb<<<nb + 32, SCAN_B, 0, stream>>>(cnt, rowptr, bsum, NN, nb,
                                              W1l, W1r, W2l, W2r, wB);
    k_scan_add<<<nb, SCAN_B, 0, stream>>>(rowptr, bsum, cur, NN, E);
    k_fill<<<cb, 256, 0, stream>>>(src, dst, cur, csr, E);

    const int blocks = (NN + NT_BLK - 1) / NT_BLK;   // 3125
    k_layer<false><<<blocks, 256, 0, stream>>>(
        xb, rowptr, csr, (const bf16x8*)wB, b1, Wfc, bfc, h1);
    k_layer<true><<<blocks, 256, 0, stream>>>(
        h1, rowptr, csr, (const bf16x8*)(wB + 32768), b2, Wfc, bfc, d_out);
}